// Round 14
// baseline (85.935 us; speedup 1.0000x reference)
//
#include <hip/hip_runtime.h>
#include <hip/hip_bf16.h>
#include <stdint.h>

// Problem constants (match reference)
#define NN      4096
#define IN_DIM  1024
#define HID     128
#define RF      896          // (2^(K+1)-1)*HID
#define NW      128          // words per bitmask row (4096/32)
#define CAP1    64           // adj1 stride (1-hop deg ~16, max ~40)
#define CAP2    1024         // adj2 stride (2-hop deg ~240)
#define KS      8            // split-K chunks for embed gemm
#define KC      (IN_DIM/KS)  // 128
#define XSTR    136          // padded LDS stride (shorts)

typedef __attribute__((ext_vector_type(8))) short   bf16x8;
typedef __attribute__((ext_vector_type(4))) float   f32x4;
typedef __attribute__((ext_vector_type(2))) float   f32x2;

static __device__ __forceinline__ uint16_t f2bf(float f) {
    __hip_bfloat16 h = __float2bfloat16(f);   // RNE
    return *reinterpret_cast<uint16_t*>(&h);
}
static __device__ __forceinline__ float bf2f(uint16_t u) {
    __hip_bfloat16 h = *reinterpret_cast<__hip_bfloat16*>(&u);
    return __bfloat162float(h);
}
static __device__ __forceinline__ uint32_t packbf(float lo, float hi) {
    return (uint32_t)f2bf(lo) | ((uint32_t)f2bf(hi) << 16);
}
// fp8 e4m3 pack/unpack via gfx950 HW converters (select arg must be imm const)
template<int HI>
static __device__ __forceinline__ uint32_t pk8(float a, float b, uint32_t old) {
    return __builtin_amdgcn_cvt_pk_fp8_f32(a, b, old, HI);
}
template<int HI>
static __device__ __forceinline__ f32x2 upk8(uint32_t u) {
    return __builtin_amdgcn_cvt_pk_f32_fp8(u, HI);
}

// ---------------------------------------------------------------------------
// 0) prep: zero Abits (blocks 0..511), zero P pad rows (block 512),
//    convert W -> transposed bf16 hi/lo (blocks 513..640, 128 thr active)
__global__ __launch_bounds__(256) void prep(
    uint32_t* __restrict__ Abits, uint32_t* __restrict__ p10, uint32_t* __restrict__ p20,
    uint32_t* __restrict__ p11, uint32_t* __restrict__ p21,
    const float* __restrict__ W, uint16_t* __restrict__ Wt_hi, uint16_t* __restrict__ Wt_lo)
{
    int b = blockIdx.x, t = threadIdx.x;
    if (b < 512) {
        reinterpret_cast<uint4*>(Abits)[b * 256 + t] = make_uint4(0, 0, 0, 0);
    } else if (b == 512) {
        // fp8 pad rows: P*_0 = 128 B (32 uints), P*_1 = 256 B (64 uints)
        if (t < 32) { p10[(size_t)NN * 32 + t] = 0; p20[(size_t)NN * 32 + t] = 0; }
        if (t < 64) { p11[(size_t)NN * 64 + t] = 0; p21[(size_t)NN * 64 + t] = 0; }
    } else {
        if (t < 128) {
            int n  = t;
            int k0 = (b - 513) * 8;
            uint16_t h[8], l[8];
            #pragma unroll
            for (int j = 0; j < 8; ++j) {
                float x = W[(size_t)(k0 + j) * HID + n];
                h[j] = f2bf(x);
                l[j] = f2bf(x - bf2f(h[j]));
            }
            ushort4* ph = reinterpret_cast<ushort4*>(Wt_hi + (size_t)n * IN_DIM + k0);
            ushort4* pl = reinterpret_cast<ushort4*>(Wt_lo + (size_t)n * IN_DIM + k0);
            ph[0] = make_ushort4(h[0], h[1], h[2], h[3]);
            ph[1] = make_ushort4(h[4], h[5], h[6], h[7]);
            pl[0] = make_ushort4(l[0], l[1], l[2], l[3]);
            pl[1] = make_ushort4(l[4], l[5], l[6], l[7]);
        }
    }
}

// ---------------------------------------------------------------------------
// 1) scatter edges into bitmask adjacency  A[src][dst] = 1
__global__ void scatter_edges(const int* __restrict__ ei, uint32_t* __restrict__ Abits, int nE) {
    int e = blockIdx.x * blockDim.x + threadIdx.x;
    if (e < nE) {
        int s = ei[e];
        int d = ei[nE + e];
        atomicOr(&Abits[(size_t)s * NW + (d >> 5)], 1u << (d & 31));
    }
}

// ---------------------------------------------------------------------------
// 2) build_embed: fused dual-role kernel. Even blocks: twohop (bit-sliced
//    threshold counters, wave-per-row). Odd blocks: embed MFMA GEMM chunk.
//    Independent work -> overlap on-CU; one launch instead of two.
#define UPD(v) { s3x |= s2x & (v).x; s2x |= s1x & (v).x; s1x |= (v).x; \
                 s3y |= s2y & (v).y; s2y |= s1y & (v).y; s1y |= (v).y; }
__global__ __launch_bounds__(256) void build_embed(
    const uint32_t* __restrict__ Abits,
    uint16_t* __restrict__ adj1, uint16_t* __restrict__ adj2,
    int* __restrict__ deg1p, int* __restrict__ deg2p,
    float* __restrict__ d1, float* __restrict__ d2,
    const float* __restrict__ X, const uint16_t* __restrict__ Wt_hi,
    const uint16_t* __restrict__ Wt_lo, float* __restrict__ partials)
{
    __shared__ __align__(16) uint16_t smem[192 * XSTR];   // 52224 B union

    int b = blockIdx.x, t = threadIdx.x;

    if ((b & 1) == 0) {
        // ================= twohop role (block id h = b>>1) =================
        uint16_t (*l1s)[CAP1] = reinterpret_cast<uint16_t(*)[CAP1]>(smem);
        int h = b >> 1;
        int wv = t >> 6, lane = t & 63;
        int i = h * 4 + wv;

        uint2 sv = *reinterpret_cast<const uint2*>(&Abits[(size_t)i * NW + lane * 2]);

        int pc1 = __popc(sv.x) + __popc(sv.y);
        int x1 = pc1;
        #pragma unroll
        for (int off = 1; off < 64; off <<= 1) {
            int y = __shfl_up(x1, off);
            if (lane >= off) x1 += y;
        }
        int tot1 = __shfl(x1, 63);
        int o = x1 - pc1;                       // exclusive prefix
        {
            uint32_t bb_ = sv.x;
            while (bb_) { int bb = __ffs(bb_) - 1; bb_ &= bb_ - 1;
                          uint16_t v = (uint16_t)(lane * 64 + bb);
                          l1s[wv][o] = v; adj1[(size_t)i * CAP1 + o] = v; ++o; }
            bb_ = sv.y;
            while (bb_) { int bb = __ffs(bb_) - 1; bb_ &= bb_ - 1;
                          uint16_t v = (uint16_t)(lane * 64 + 32 + bb);
                          l1s[wv][o] = v; adj1[(size_t)i * CAP1 + o] = v; ++o; }
        }
        int n1 = (tot1 + 3) & ~3;
        if (lane == 0) {
            for (int z = tot1; z < n1; ++z) adj1[(size_t)i * CAP1 + z] = (uint16_t)NN;
            deg1p[i] = n1;
            d1[i] = rsqrtf((float)tot1 + 1e-8f);
        }
        __syncthreads();

        uint32_t s1x = 0, s2x = 0, s3x = 0, s1y = 0, s2y = 0, s3y = 0;
        int m = 0;
        for (; m + 4 <= tot1; m += 4) {
            int k0 = l1s[wv][m], k1 = l1s[wv][m + 1], k2 = l1s[wv][m + 2], k3 = l1s[wv][m + 3];
            uint2 a = *reinterpret_cast<const uint2*>(&Abits[(size_t)k0 * NW + lane * 2]);
            uint2 bq = *reinterpret_cast<const uint2*>(&Abits[(size_t)k1 * NW + lane * 2]);
            uint2 c = *reinterpret_cast<const uint2*>(&Abits[(size_t)k2 * NW + lane * 2]);
            uint2 d = *reinterpret_cast<const uint2*>(&Abits[(size_t)k3 * NW + lane * 2]);
            UPD(a); UPD(bq); UPD(c); UPD(d);
        }
        for (; m < tot1; ++m) {
            int k = l1s[wv][m];
            uint2 a = *reinterpret_cast<const uint2*>(&Abits[(size_t)k * NW + lane * 2]);
            UPD(a);
        }

        uint32_t iwx = ((i >> 5) == lane * 2)     ? (1u << (i & 31)) : 0u;
        uint32_t iwy = ((i >> 5) == lane * 2 + 1) ? (1u << (i & 31)) : 0u;
        uint32_t a2x = (s1x & ~sv.x & ~iwx) | (s2x & (sv.x ^ iwx)) | (s3x & (sv.x & iwx));
        uint32_t a2y = (s1y & ~sv.y & ~iwy) | (s2y & (sv.y ^ iwy)) | (s3y & (sv.y & iwy));

        int pc2 = __popc(a2x) + __popc(a2y);
        int x2 = pc2;
        #pragma unroll
        for (int off = 1; off < 64; off <<= 1) {
            int y = __shfl_up(x2, off);
            if (lane >= off) x2 += y;
        }
        int tot2 = __shfl(x2, 63);
        o = x2 - pc2;
        {
            uint32_t bb_ = a2x;
            while (bb_) { int bb = __ffs(bb_) - 1; bb_ &= bb_ - 1;
                          adj2[(size_t)i * CAP2 + o] = (uint16_t)(lane * 64 + bb); ++o; }
            bb_ = a2y;
            while (bb_) { int bb = __ffs(bb_) - 1; bb_ &= bb_ - 1;
                          adj2[(size_t)i * CAP2 + o] = (uint16_t)(lane * 64 + 32 + bb); ++o; }
        }
        int n2 = (tot2 + 3) & ~3;
        if (lane == 0) {
            for (int z = tot2; z < n2; ++z) adj2[(size_t)i * CAP2 + z] = (uint16_t)NN;
            deg2p[i] = n2;
            d2[i] = rsqrtf((float)tot2 + 1e-8f);
        }
    } else {
        // ================= embed role (block id e = b>>1) ==================
        uint16_t (*XhiS)[XSTR] = reinterpret_cast<uint16_t(*)[XSTR]>(smem);
        uint16_t (*XloS)[XSTR] = reinterpret_cast<uint16_t(*)[XSTR]>(smem + 32 * XSTR);
        uint16_t (*WS)[XSTR]   = reinterpret_cast<uint16_t(*)[XSTR]>(smem + 64 * XSTR);

        int e  = b >> 1;
        int m0 = (e & 127) * 32;
        int kc = e >> 7;

        // stage X tile (32 x KC fp32) -> hi/lo bf16  (256 threads, 4 iters)
        #pragma unroll
        for (int u = 0; u < 4; ++u) {
            int q = u * 256 + t;
            int row = q >> 5, c4 = q & 31;
            float4 xv = *reinterpret_cast<const float4*>(
                X + (size_t)(m0 + row) * IN_DIM + kc * KC + c4 * 4);
            ushort4 hv, lv;
            hv.x = f2bf(xv.x); lv.x = f2bf(xv.x - bf2f(hv.x));
            hv.y = f2bf(xv.y); lv.y = f2bf(xv.y - bf2f(hv.y));
            hv.z = f2bf(xv.z); lv.z = f2bf(xv.z - bf2f(hv.z));
            hv.w = f2bf(xv.w); lv.w = f2bf(xv.w - bf2f(hv.w));
            *reinterpret_cast<ushort4*>(&XhiS[row][c4 * 4]) = hv;
            *reinterpret_cast<ushort4*>(&XloS[row][c4 * 4]) = lv;
        }
        // stage W_hi tile (128 n x KC k)  (256 threads, 8 iters)
        #pragma unroll
        for (int u = 0; u < 8; ++u) {
            int q = u * 256 + t;
            int n = q >> 4, ck = q & 15;
            *reinterpret_cast<uint4*>(&WS[n][ck * 8]) =
                *reinterpret_cast<const uint4*>(Wt_hi + (size_t)n * IN_DIM + kc * KC + ck * 8);
        }
        __syncthreads();

        int w = t >> 6, lane = t & 63;
        int nr = lane & 15, g = lane >> 4;
        f32x4 acc[8] = {};
        bf16x8 ah[4], al[4];

        if (t < 128) {
            int arow = w * 16 + nr;
            #pragma unroll
            for (int s = 0; s < 4; ++s) {
                ah[s] = *reinterpret_cast<const bf16x8*>(&XhiS[arow][s * 32 + g * 8]);
                al[s] = *reinterpret_cast<const bf16x8*>(&XloS[arow][s * 32 + g * 8]);
            }
            #pragma unroll
            for (int s = 0; s < 4; ++s)
                #pragma unroll
                for (int nf = 0; nf < 8; ++nf) {
                    bf16x8 bb = *reinterpret_cast<const bf16x8*>(&WS[nf * 16 + nr][s * 32 + g * 8]);
                    acc[nf] = __builtin_amdgcn_mfma_f32_16x16x32_bf16(ah[s], bb, acc[nf], 0, 0, 0);
                    acc[nf] = __builtin_amdgcn_mfma_f32_16x16x32_bf16(al[s], bb, acc[nf], 0, 0, 0);
                }
        }
        __syncthreads();
        // stage W_lo
        #pragma unroll
        for (int u = 0; u < 8; ++u) {
            int q = u * 256 + t;
            int n = q >> 4, ck = q & 15;
            *reinterpret_cast<uint4*>(&WS[n][ck * 8]) =
                *reinterpret_cast<const uint4*>(Wt_lo + (size_t)n * IN_DIM + kc * KC + ck * 8);
        }
        __syncthreads();
        if (t < 128) {
            #pragma unroll
            for (int s = 0; s < 4; ++s)
                #pragma unroll
                for (int nf = 0; nf < 8; ++nf) {
                    bf16x8 bb = *reinterpret_cast<const bf16x8*>(&WS[nf * 16 + nr][s * 32 + g * 8]);
                    acc[nf] = __builtin_amdgcn_mfma_f32_16x16x32_bf16(ah[s], bb, acc[nf], 0, 0, 0);
                }

            float* part = partials + (size_t)kc * NN * HID;
            #pragma unroll
            for (int nf = 0; nf < 8; ++nf)
                #pragma unroll
                for (int r = 0; r < 4; ++r)
                    part[(size_t)(m0 + w * 16 + g * 4 + r) * HID + nf * 16 + nr] = acc[nf][r];
        }
    }
}

// ---------------------------------------------------------------------------
// 3c) reduce split-K partials + bias + relu -> rf bf16 (cols 0:128) +
//     P1_0/P2_0 in fp8 e4m3 (pre-scaled by d1/d2)
__global__ void embed_reduce(const float* __restrict__ partials, const float* __restrict__ bias,
                             const float* __restrict__ d1, const float* __restrict__ d2,
                             uint16_t* __restrict__ rfb, uint32_t* __restrict__ P1,
                             uint32_t* __restrict__ P2) {
    int idx = blockIdx.x * blockDim.x + threadIdx.x;
    size_t off = (size_t)idx * 4;
    int row = (int)(off >> 7);
    int col = (int)(off & 127);

    float4 s = make_float4(0.f, 0.f, 0.f, 0.f);
    #pragma unroll
    for (int kc = 0; kc < KS; ++kc) {
        float4 p = *reinterpret_cast<const float4*>(partials + (size_t)kc * NN * HID + off);
        s.x += p.x; s.y += p.y; s.z += p.z; s.w += p.w;
    }
    float4 bv = *reinterpret_cast<const float4*>(bias + col);
    float4 v;
    v.x = fmaxf(s.x + bv.x, 0.f);
    v.y = fmaxf(s.y + bv.y, 0.f);
    v.z = fmaxf(s.z + bv.z, 0.f);
    v.w = fmaxf(s.w + bv.w, 0.f);

    uint2 rv;
    rv.x = packbf(v.x, v.y); rv.y = packbf(v.z, v.w);
    *reinterpret_cast<uint2*>(rfb + (size_t)row * RF + col) = rv;

    float s1 = d1[row], s2 = d2[row];
    uint32_t w1 = pk8<0>(s1 * v.x, s1 * v.y, 0u);
    w1 = pk8<1>(s1 * v.z, s1 * v.w, w1);
    P1[(size_t)row * 32 + (col >> 2)] = w1;
    uint32_t w2 = pk8<0>(s2 * v.x, s2 * v.y, 0u);
    w2 = pk8<1>(s2 * v.z, s2 * v.w, w2);
    P2[(size_t)row * 32 + (col >> 2)] = w2;
}

// ---------------------------------------------------------------------------
// 4a) hop-1 gather (fp8 operand). Wave task gw: i = gw>>1, mat = gw&1.
//     Scalar adj fetch; lane reads uint2 = 8 fp8 values.
__global__ __launch_bounds__(256) void gather_k1(
    const uint16_t* __restrict__ adj1, const uint16_t* __restrict__ adj2,
    const int* __restrict__ deg1p, const int* __restrict__ deg2p,
    const uint32_t* __restrict__ P10, const uint32_t* __restrict__ P20,
    const float* __restrict__ d1, const float* __restrict__ d2,
    uint16_t* __restrict__ rfb, uint32_t* __restrict__ P11, uint32_t* __restrict__ P21)
{
    int lane = threadIdx.x & 63;
    int gw   = __builtin_amdgcn_readfirstlane((blockIdx.x * 256 + threadIdx.x) >> 6);
    int i    = gw >> 1;
    int mat  = gw & 1;
    int nb = lane >> 4, cq = lane & 15;
    int shamt = lane & 48;               // nb*16

    const uint16_t* adj = mat ? adj2 + (size_t)i * CAP2 : adj1 + (size_t)i * CAP1;
    int n = (mat ? deg2p : deg1p)[i];
    const uint32_t* P = mat ? P20 : P10;

    f32x2 acc[4] = {};
    #pragma unroll 8
    for (int m = 0; m < n; m += 4) {
        uint64_t aw = *reinterpret_cast<const uint64_t*>(adj + m);   // uniform -> s_load
        int j = (int)((uint32_t)(aw >> shamt) & 0xffffu);
        uint2 u = *reinterpret_cast<const uint2*>(P + (size_t)j * 32 + cq * 2);
        acc[0] += upk8<0>(u.x);
        acc[1] += upk8<1>(u.x);
        acc[2] += upk8<0>(u.y);
        acc[3] += upk8<1>(u.y);
    }
    #pragma unroll
    for (int k = 0; k < 4; ++k) {
        acc[k].x += __shfl_xor(acc[k].x, 16); acc[k].y += __shfl_xor(acc[k].y, 16);
        acc[k].x += __shfl_xor(acc[k].x, 32); acc[k].y += __shfl_xor(acc[k].y, 32);
    }

    if (nb == 0) {
        float di = (mat ? d2 : d1)[i];
        float o[8];
        #pragma unroll
        for (int k = 0; k < 4; ++k) { o[2 * k] = di * acc[k].x; o[2 * k + 1] = di * acc[k].y; }

        uint4 rv;
        rv.x = packbf(o[0], o[1]); rv.y = packbf(o[2], o[3]);
        rv.z = packbf(o[4], o[5]); rv.w = packbf(o[6], o[7]);
        *reinterpret_cast<uint4*>(rfb + (size_t)i * RF + 128 + mat * 128 + cq * 8) = rv;

        float s1 = d1[i], s2 = d2[i];
        uint2 v1, v2;
        v1.x = pk8<0>(s1 * o[0], s1 * o[1], 0u);
        v1.x = pk8<1>(s1 * o[2], s1 * o[3], v1.x);
        v1.y = pk8<0>(s1 * o[4], s1 * o[5], 0u);
        v1.y = pk8<1>(s1 * o[6], s1 * o[7], v1.y);
        v2.x = pk8<0>(s2 * o[0], s2 * o[1], 0u);
        v2.x = pk8<1>(s2 * o[2], s2 * o[3], v2.x);
        v2.y = pk8<0>(s2 * o[4], s2 * o[5], 0u);
        v2.y = pk8<1>(s2 * o[6], s2 * o[7], v2.y);
        *reinterpret_cast<uint2*>(P11 + (size_t)i * 64 + mat * 32 + cq * 2) = v1;
        *reinterpret_cast<uint2*>(P21 + (size_t)i * 64 + mat * 32 + cq * 2) = v2;
    }
}

// ---------------------------------------------------------------------------
// 4b) hop-2 gather (fp8 operand), barrier-free, segment-grouped, scalar adj.
//     Grid 4096 blocks: seg = b>>10 (mat=seg>>1, half=seg&1), i = (b&1023)*4+wv.
__global__ __launch_bounds__(256) void gather_k2(
    const uint16_t* __restrict__ adj1, const uint16_t* __restrict__ adj2,
    const int* __restrict__ deg1p, const int* __restrict__ deg2p,
    const uint32_t* __restrict__ P11, const uint32_t* __restrict__ P21,
    const float* __restrict__ d1, const float* __restrict__ d2,
    uint16_t* __restrict__ rfb)
{
    int wv   = threadIdx.x >> 6;
    int lane = threadIdx.x & 63;
    int seg  = blockIdx.x >> 10;
    int i    = __builtin_amdgcn_readfirstlane((blockIdx.x & 1023) * 4 + wv);
    int mat  = seg >> 1;
    int half = seg & 1;
    int nb = lane >> 4, cq = lane & 15;
    int shamt = lane & 48;               // nb*16

    const uint16_t* adj = mat ? adj2 + (size_t)i * CAP2 : adj1 + (size_t)i * CAP1;
    int n = (mat ? deg2p : deg1p)[i];
    const uint32_t* P = (mat ? P21 : P11) + half * 32 + cq * 2;

    f32x2 acc[4] = {};
    #pragma unroll 8
    for (int m = 0; m < n; m += 4) {
        uint64_t aw = *reinterpret_cast<const uint64_t*>(adj + m);   // uniform -> s_load
        int j = (int)((uint32_t)(aw >> shamt) & 0xffffu);
        uint2 u = *reinterpret_cast<const uint2*>(P + (size_t)j * 64);
        acc[0] += upk8<0>(u.x);
        acc[1] += upk8<1>(u.x);
        acc[2] += upk8<0>(u.y);
        acc[3] += upk8<1>(u.y);
    }
    #pragma unroll
    for (int k = 0; k < 4; ++k) {
        acc[k].x += __shfl_xor(acc[k].x, 16); acc[k].y += __shfl_xor(acc[k].y, 16);
        acc[k].x += __shfl_xor(acc[k].x, 32); acc[k].y += __shfl_xor(acc[k].y, 32);
    }

    if (nb == 0) {
        float di = (mat ? d2 : d1)[i];
        int colbase = 384 + mat * 256 + half * 128 + cq * 8;
        uint4 rv;
        rv.x = packbf(di * acc[0].x, di * acc[0].y);
        rv.y = packbf(di * acc[1].x, di * acc[1].y);
        rv.z = packbf(di * acc[2].x, di * acc[2].y);
        rv.w = packbf(di * acc[3].x, di * acc[3].y);
        *reinterpret_cast<uint4*>(rfb + (size_t)i * RF + colbase) = rv;
    }
}

// ---------------------------------------------------------------------------
// 5) classifier GEMM over bf16 rf: out = rf @ Wc + bc. Wave-per-row.
__global__ __launch_bounds__(256) void cls_bf(
    const uint16_t* __restrict__ rfb, const float* __restrict__ Wc,
    const float* __restrict__ bc, float* __restrict__ out)
{
    int wave = threadIdx.x >> 6;
    int lane = threadIdx.x & 63;
    int row  = blockIdx.x * 4 + wave;

    const uint32_t* rp = reinterpret_cast<const uint32_t*>(rfb + (size_t)row * RF);
    float acc[10] = {};
    #pragma unroll
    for (int k7 = 0; k7 < 7; ++k7) {
        int k = k7 * 64 + lane;          // uint index 0..447 (col pair 2k,2k+1)
        uint32_t u = rp[k];
        float x0 = __uint_as_float(u << 16);
        float x1 = __uint_as_float(u & 0xffff0000u);
        const float* w = Wc + (size_t)k * 20;
        #pragma unroll
        for (int c = 0; c < 10; ++c) acc[c] += x0 * w[c] + x1 * w[10 + c];
    }
    #pragma unroll
    for (int c = 0; c < 10; ++c)
        #pragma unroll
        for (int off = 32; off; off >>= 1) acc[c] += __shfl_down(acc[c], off);

    if (lane == 0) {
        #pragma unroll
        for (int c = 0; c < 10; ++c) out[(size_t)row * 10 + c] = acc[c] + bc[c];
    }
}

// ---------------------------------------------------------------------------
extern "C" void kernel_launch(void* const* d_in, const int* in_sizes, int n_in,
                              void* d_out, int out_size, void* d_ws, size_t ws_size,
                              hipStream_t stream) {
    const float* X       = (const float*)d_in[0];
    const int*   ei      = (const int*)d_in[1];
    const float* W_embed = (const float*)d_in[2];
    const float* b_embed = (const float*)d_in[3];
    const float* W_cls   = (const float*)d_in[4];
    const float* b_cls   = (const float*)d_in[5];
    float* out = (float*)d_out;

    int nE = in_sizes[1] / 2;

    // workspace layout (all 16B-aligned)
    uint32_t* Abits = (uint32_t*)d_ws;                         // 2 MB
    float* d1 = (float*)(Abits + (size_t)NN * NW);             // 16 KB
    float* d2 = d1 + NN;                                       // 16 KB
    uint16_t* rfb = (uint16_t*)(d2 + NN);                      // 7.34 MB bf16 [NN][RF]
    uint32_t* P1_0 = (uint32_t*)(rfb + (size_t)NN * RF);       // fp8 [NN+1][128] = 512 KB
    uint32_t* P2_0 = P1_0 + (size_t)(NN + 1) * 32;
    uint32_t* P1_1 = P2_0 + (size_t)(NN + 1) * 32;             // fp8 [NN+1][256] = 1 MB
    uint32_t* P2_1 = P1_1 + (size_t)(NN + 1) * 64;
    uint16_t* Wt_hi = (uint16_t*)(P2_1 + (size_t)(NN + 1) * 64);  // 256 KB
    uint16_t* Wt_lo = Wt_hi + (size_t)HID * IN_DIM;            // 256 KB
    float* partials = (float*)(Wt_lo + (size_t)HID * IN_DIM);  // 16 MB [KS][NN][128]
    uint16_t* adj1 = (uint16_t*)(partials + (size_t)KS * NN * HID); // 512 KB
    uint16_t* adj2 = adj1 + (size_t)NN * CAP1;                 // 8 MB
    int* deg1p = (int*)(adj2 + (size_t)NN * CAP2);             // 16 KB
    int* deg2p = deg1p + NN;                                   // 16 KB

    prep<<<641, 256, 0, stream>>>(Abits, P1_0, P2_0, P1_1, P2_1,
                                  W_embed, Wt_hi, Wt_lo);
    scatter_edges<<<(nE + 255) / 256, 256, 0, stream>>>(ei, Abits, nE);

    build_embed<<<2048, 256, 0, stream>>>(Abits, adj1, adj2, deg1p, deg2p, d1, d2,
                                          X, Wt_hi, Wt_lo, partials);

    embed_reduce<<<(NN * HID / 4) / 256, 256, 0, stream>>>(partials, b_embed, d1, d2,
                                                           rfb, P1_0, P2_0);

    gather_k1<<<NN * 2 * 64 / 256, 256, 0, stream>>>(
        adj1, adj2, deg1p, deg2p, P1_0, P2_0, d1, d2, rfb, P1_1, P2_1);
    gather_k2<<<NN * 4 * 64 / 256, 256, 0, stream>>>(
        adj1, adj2, deg1p, deg2p, P1_1, P2_1, d1, d2, rfb);

    cls_bf<<<NN / 4, 256, 0, stream>>>(rfb, W_cls, b_cls, out);
}

// Round 15
// 83.483 us; speedup vs baseline: 1.0294x; 1.0294x over previous
//
#include <hip/hip_runtime.h>
#include <hip/hip_bf16.h>
#include <stdint.h>

// Problem constants (match reference)
#define NN      4096
#define IN_DIM  1024
#define HID     128
#define RF      896          // (2^(K+1)-1)*HID
#define NW      128          // words per bitmask row (4096/32)
#define CAP1    64           // adj1 stride (1-hop deg ~16, max ~40)
#define CAP2    1024         // adj2 stride (2-hop deg ~240)
#define KS      4            // split-K chunks for embed gemm (2 sub-chunks each)
#define KC      256          // columns per kc block (2 x 128 staging sub-chunks)

typedef __attribute__((ext_vector_type(8))) short   bf16x8;
typedef __attribute__((ext_vector_type(4))) float   f32x4;
typedef __attribute__((ext_vector_type(2))) float   f32x2;

static __device__ __forceinline__ uint16_t f2bf(float f) {
    __hip_bfloat16 h = __float2bfloat16(f);   // RNE
    return *reinterpret_cast<uint16_t*>(&h);
}
static __device__ __forceinline__ float bf2f(uint16_t u) {
    __hip_bfloat16 h = *reinterpret_cast<__hip_bfloat16*>(&u);
    return __bfloat162float(h);
}
static __device__ __forceinline__ uint32_t packbf(float lo, float hi) {
    return (uint32_t)f2bf(lo) | ((uint32_t)f2bf(hi) << 16);
}
// fp8 e4m3 pack/unpack via gfx950 HW converters (select arg must be imm const)
template<int HI>
static __device__ __forceinline__ uint32_t pk8(float a, float b, uint32_t old) {
    return __builtin_amdgcn_cvt_pk_fp8_f32(a, b, old, HI);
}
template<int HI>
static __device__ __forceinline__ f32x2 upk8(uint32_t u) {
    return __builtin_amdgcn_cvt_pk_f32_fp8(u, HI);
}

// ---------------------------------------------------------------------------
// 0) prep: zero Abits (blocks 0..511), zero P pad rows (block 512),
//    convert W -> transposed bf16 hi/lo (blocks 513..640, 128 thr active)
__global__ __launch_bounds__(256) void prep(
    uint32_t* __restrict__ Abits, uint32_t* __restrict__ p10, uint32_t* __restrict__ p20,
    uint32_t* __restrict__ p11, uint32_t* __restrict__ p21,
    const float* __restrict__ W, uint16_t* __restrict__ Wt_hi, uint16_t* __restrict__ Wt_lo)
{
    int b = blockIdx.x, t = threadIdx.x;
    if (b < 512) {
        reinterpret_cast<uint4*>(Abits)[b * 256 + t] = make_uint4(0, 0, 0, 0);
    } else if (b == 512) {
        // fp8 pad rows: P*_0 = 128 B (32 uints), P*_1 = 256 B (64 uints)
        if (t < 32) { p10[(size_t)NN * 32 + t] = 0; p20[(size_t)NN * 32 + t] = 0; }
        if (t < 64) { p11[(size_t)NN * 64 + t] = 0; p21[(size_t)NN * 64 + t] = 0; }
    } else {
        if (t < 128) {
            int n  = t;
            int k0 = (b - 513) * 8;
            uint16_t h[8], l[8];
            #pragma unroll
            for (int j = 0; j < 8; ++j) {
                float x = W[(size_t)(k0 + j) * HID + n];
                h[j] = f2bf(x);
                l[j] = f2bf(x - bf2f(h[j]));
            }
            ushort4* ph = reinterpret_cast<ushort4*>(Wt_hi + (size_t)n * IN_DIM + k0);
            ushort4* pl = reinterpret_cast<ushort4*>(Wt_lo + (size_t)n * IN_DIM + k0);
            ph[0] = make_ushort4(h[0], h[1], h[2], h[3]);
            ph[1] = make_ushort4(h[4], h[5], h[6], h[7]);
            pl[0] = make_ushort4(l[0], l[1], l[2], l[3]);
            pl[1] = make_ushort4(l[4], l[5], l[6], l[7]);
        }
    }
}

// ---------------------------------------------------------------------------
// 1) scatter edges into bitmask adjacency  A[src][dst] = 1
__global__ void scatter_edges(const int* __restrict__ ei, uint32_t* __restrict__ Abits, int nE) {
    int e = blockIdx.x * blockDim.x + threadIdx.x;
    if (e < nE) {
        int s = ei[e];
        int d = ei[nE + e];
        atomicOr(&Abits[(size_t)s * NW + (d >> 5)], 1u << (d & 31));
    }
}

// ---------------------------------------------------------------------------
// 2) twohop2: bit-sliced threshold counters, wave-per-row (4 waves/block).
#define UPD(v) { s3x |= s2x & (v).x; s2x |= s1x & (v).x; s1x |= (v).x; \
                 s3y |= s2y & (v).y; s2y |= s1y & (v).y; s1y |= (v).y; }
__global__ __launch_bounds__(256) void twohop2(
    const uint32_t* __restrict__ Abits,
    uint16_t* __restrict__ adj1, uint16_t* __restrict__ adj2,
    int* __restrict__ deg1p, int* __restrict__ deg2p,
    float* __restrict__ d1, float* __restrict__ d2)
{
    __shared__ uint16_t l1s[4][CAP1];

    int wv = threadIdx.x >> 6, lane = threadIdx.x & 63;
    int i = blockIdx.x * 4 + wv;

    uint2 sv = *reinterpret_cast<const uint2*>(&Abits[(size_t)i * NW + lane * 2]);

    // ---- adj1: scan + emit
    int pc1 = __popc(sv.x) + __popc(sv.y);
    int x1 = pc1;
    #pragma unroll
    for (int off = 1; off < 64; off <<= 1) {
        int y = __shfl_up(x1, off);
        if (lane >= off) x1 += y;
    }
    int tot1 = __shfl(x1, 63);
    int o = x1 - pc1;                       // exclusive prefix
    {
        uint32_t b = sv.x;
        while (b) { int bb = __ffs(b) - 1; b &= b - 1;
                    uint16_t v = (uint16_t)(lane * 64 + bb);
                    l1s[wv][o] = v; adj1[(size_t)i * CAP1 + o] = v; ++o; }
        b = sv.y;
        while (b) { int bb = __ffs(b) - 1; b &= b - 1;
                    uint16_t v = (uint16_t)(lane * 64 + 32 + bb);
                    l1s[wv][o] = v; adj1[(size_t)i * CAP1 + o] = v; ++o; }
    }
    int n1 = (tot1 + 3) & ~3;
    if (lane == 0) {
        for (int z = tot1; z < n1; ++z) adj1[(size_t)i * CAP1 + z] = (uint16_t)NN;
        deg1p[i] = n1;
        d1[i] = rsqrtf((float)tot1 + 1e-8f);
    }
    __syncthreads();

    // ---- path-count thresholds over neighbors
    uint32_t s1x = 0, s2x = 0, s3x = 0, s1y = 0, s2y = 0, s3y = 0;
    int m = 0;
    for (; m + 4 <= tot1; m += 4) {
        int k0 = l1s[wv][m], k1 = l1s[wv][m + 1], k2 = l1s[wv][m + 2], k3 = l1s[wv][m + 3];
        uint2 a = *reinterpret_cast<const uint2*>(&Abits[(size_t)k0 * NW + lane * 2]);
        uint2 b = *reinterpret_cast<const uint2*>(&Abits[(size_t)k1 * NW + lane * 2]);
        uint2 c = *reinterpret_cast<const uint2*>(&Abits[(size_t)k2 * NW + lane * 2]);
        uint2 d = *reinterpret_cast<const uint2*>(&Abits[(size_t)k3 * NW + lane * 2]);
        UPD(a); UPD(b); UPD(c); UPD(d);
    }
    for (; m < tot1; ++m) {
        int k = l1s[wv][m];
        uint2 a = *reinterpret_cast<const uint2*>(&Abits[(size_t)k * NW + lane * 2]);
        UPD(a);
    }

    uint32_t iwx = ((i >> 5) == lane * 2)     ? (1u << (i & 31)) : 0u;
    uint32_t iwy = ((i >> 5) == lane * 2 + 1) ? (1u << (i & 31)) : 0u;
    uint32_t a2x = (s1x & ~sv.x & ~iwx) | (s2x & (sv.x ^ iwx)) | (s3x & (sv.x & iwx));
    uint32_t a2y = (s1y & ~sv.y & ~iwy) | (s2y & (sv.y ^ iwy)) | (s3y & (sv.y & iwy));

    // ---- adj2: scan + emit
    int pc2 = __popc(a2x) + __popc(a2y);
    int x2 = pc2;
    #pragma unroll
    for (int off = 1; off < 64; off <<= 1) {
        int y = __shfl_up(x2, off);
        if (lane >= off) x2 += y;
    }
    int tot2 = __shfl(x2, 63);
    o = x2 - pc2;
    {
        uint32_t b = a2x;
        while (b) { int bb = __ffs(b) - 1; b &= b - 1;
                    adj2[(size_t)i * CAP2 + o] = (uint16_t)(lane * 64 + bb); ++o; }
        b = a2y;
        while (b) { int bb = __ffs(b) - 1; b &= b - 1;
                    adj2[(size_t)i * CAP2 + o] = (uint16_t)(lane * 64 + 32 + bb); ++o; }
    }
    int n2 = (tot2 + 3) & ~3;
    if (lane == 0) {
        for (int z = tot2; z < n2; ++z) adj2[(size_t)i * CAP2 + z] = (uint16_t)NN;
        deg2p[i] = n2;
        d2[i] = rsqrtf((float)tot2 + 1e-8f);
    }
}

// ---------------------------------------------------------------------------
// 3b) embed MFMA GEMM, bf16x2 split, split-K (KS=4; each block loops over
//     two 128-wide k-sub-chunks, accumulating in-register).
#define XSTR 136
__global__ __launch_bounds__(128) void embed_mfma(
    const float* __restrict__ X, const uint16_t* __restrict__ Wt_hi,
    const uint16_t* __restrict__ Wt_lo, float* __restrict__ partials)
{
    __shared__ uint16_t XhiS[32][XSTR];
    __shared__ uint16_t XloS[32][XSTR];
    __shared__ uint16_t WS[128][XSTR];

    int t  = threadIdx.x;
    int m0 = blockIdx.x * 32;
    int kc = blockIdx.y;

    int w = t >> 6, lane = t & 63;
    int nr = lane & 15, g = lane >> 4;
    int arow = w * 16 + nr;

    f32x4 acc[8] = {};

    #pragma unroll
    for (int kc2 = 0; kc2 < 2; ++kc2) {
        int kOff = kc * KC + kc2 * 128;

        // stage X sub-tile (32 x 128 fp32) -> hi/lo bf16
        #pragma unroll
        for (int u = 0; u < 8; ++u) {
            int q = u * 128 + t;
            int row = q >> 5, c4 = q & 31;
            float4 xv = *reinterpret_cast<const float4*>(
                X + (size_t)(m0 + row) * IN_DIM + kOff + c4 * 4);
            ushort4 hv, lv;
            hv.x = f2bf(xv.x); lv.x = f2bf(xv.x - bf2f(hv.x));
            hv.y = f2bf(xv.y); lv.y = f2bf(xv.y - bf2f(hv.y));
            hv.z = f2bf(xv.z); lv.z = f2bf(xv.z - bf2f(hv.z));
            hv.w = f2bf(xv.w); lv.w = f2bf(xv.w - bf2f(hv.w));
            *reinterpret_cast<ushort4*>(&XhiS[row][c4 * 4]) = hv;
            *reinterpret_cast<ushort4*>(&XloS[row][c4 * 4]) = lv;
        }
        // stage W_hi sub-tile (128 n x 128 k)
        #pragma unroll
        for (int u = 0; u < 16; ++u) {
            int q = u * 128 + t;
            int n = q >> 4, ck = q & 15;
            *reinterpret_cast<uint4*>(&WS[n][ck * 8]) =
                *reinterpret_cast<const uint4*>(Wt_hi + (size_t)n * IN_DIM + kOff + ck * 8);
        }
        __syncthreads();

        bf16x8 ah[4], al[4];
        #pragma unroll
        for (int s = 0; s < 4; ++s) {
            ah[s] = *reinterpret_cast<const bf16x8*>(&XhiS[arow][s * 32 + g * 8]);
            al[s] = *reinterpret_cast<const bf16x8*>(&XloS[arow][s * 32 + g * 8]);
        }

        // phase 1: Xhi@Whi + Xlo@Whi
        #pragma unroll
        for (int s = 0; s < 4; ++s)
            #pragma unroll
            for (int nf = 0; nf < 8; ++nf) {
                bf16x8 bb = *reinterpret_cast<const bf16x8*>(&WS[nf * 16 + nr][s * 32 + g * 8]);
                acc[nf] = __builtin_amdgcn_mfma_f32_16x16x32_bf16(ah[s], bb, acc[nf], 0, 0, 0);
                acc[nf] = __builtin_amdgcn_mfma_f32_16x16x32_bf16(al[s], bb, acc[nf], 0, 0, 0);
            }
        __syncthreads();
        // stage W_lo
        #pragma unroll
        for (int u = 0; u < 16; ++u) {
            int q = u * 128 + t;
            int n = q >> 4, ck = q & 15;
            *reinterpret_cast<uint4*>(&WS[n][ck * 8]) =
                *reinterpret_cast<const uint4*>(Wt_lo + (size_t)n * IN_DIM + kOff + ck * 8);
        }
        __syncthreads();
        // phase 2: Xhi@Wlo
        #pragma unroll
        for (int s = 0; s < 4; ++s)
            #pragma unroll
            for (int nf = 0; nf < 8; ++nf) {
                bf16x8 bb = *reinterpret_cast<const bf16x8*>(&WS[nf * 16 + nr][s * 32 + g * 8]);
                acc[nf] = __builtin_amdgcn_mfma_f32_16x16x32_bf16(ah[s], bb, acc[nf], 0, 0, 0);
            }
        __syncthreads();   // protect LDS before next sub-chunk restage
    }

    float* part = partials + (size_t)kc * NN * HID;
    #pragma unroll
    for (int nf = 0; nf < 8; ++nf)
        #pragma unroll
        for (int r = 0; r < 4; ++r)
            part[(size_t)(m0 + w * 16 + g * 4 + r) * HID + nf * 16 + nr] = acc[nf][r];
}

// ---------------------------------------------------------------------------
// 3c) reduce split-K partials + bias + relu -> rf bf16 (cols 0:128) +
//     P1_0/P2_0 in fp8 e4m3 (pre-scaled by d1/d2)
__global__ void embed_reduce(const float* __restrict__ partials, const float* __restrict__ bias,
                             const float* __restrict__ d1, const float* __restrict__ d2,
                             uint16_t* __restrict__ rfb, uint32_t* __restrict__ P1,
                             uint32_t* __restrict__ P2) {
    int idx = blockIdx.x * blockDim.x + threadIdx.x;
    size_t off = (size_t)idx * 4;
    int row = (int)(off >> 7);
    int col = (int)(off & 127);

    float4 s = make_float4(0.f, 0.f, 0.f, 0.f);
    #pragma unroll
    for (int kc = 0; kc < KS; ++kc) {
        float4 p = *reinterpret_cast<const float4*>(partials + (size_t)kc * NN * HID + off);
        s.x += p.x; s.y += p.y; s.z += p.z; s.w += p.w;
    }
    float4 bv = *reinterpret_cast<const float4*>(bias + col);
    float4 v;
    v.x = fmaxf(s.x + bv.x, 0.f);
    v.y = fmaxf(s.y + bv.y, 0.f);
    v.z = fmaxf(s.z + bv.z, 0.f);
    v.w = fmaxf(s.w + bv.w, 0.f);

    uint2 rv;
    rv.x = packbf(v.x, v.y); rv.y = packbf(v.z, v.w);
    *reinterpret_cast<uint2*>(rfb + (size_t)row * RF + col) = rv;

    float s1 = d1[row], s2 = d2[row];
    uint32_t w1 = pk8<0>(s1 * v.x, s1 * v.y, 0u);
    w1 = pk8<1>(s1 * v.z, s1 * v.w, w1);
    P1[(size_t)row * 32 + (col >> 2)] = w1;
    uint32_t w2 = pk8<0>(s2 * v.x, s2 * v.y, 0u);
    w2 = pk8<1>(s2 * v.z, s2 * v.w, w2);
    P2[(size_t)row * 32 + (col >> 2)] = w2;
}

// ---------------------------------------------------------------------------
// 4a) hop-1 gather (fp8 operand). Wave task gw: i = gw>>1, mat = gw&1.
//     Scalar adj fetch; lane reads uint2 = 8 fp8 values.
__global__ __launch_bounds__(256) void gather_k1(
    const uint16_t* __restrict__ adj1, const uint16_t* __restrict__ adj2,
    const int* __restrict__ deg1p, const int* __restrict__ deg2p,
    const uint32_t* __restrict__ P10, const uint32_t* __restrict__ P20,
    const float* __restrict__ d1, const float* __restrict__ d2,
    uint16_t* __restrict__ rfb, uint32_t* __restrict__ P11, uint32_t* __restrict__ P21)
{
    int lane = threadIdx.x & 63;
    int gw   = __builtin_amdgcn_readfirstlane((blockIdx.x * 256 + threadIdx.x) >> 6);
    int i    = gw >> 1;
    int mat  = gw & 1;
    int nb = lane >> 4, cq = lane & 15;
    int shamt = lane & 48;               // nb*16

    const uint16_t* adj = mat ? adj2 + (size_t)i * CAP2 : adj1 + (size_t)i * CAP1;
    int n = (mat ? deg2p : deg1p)[i];
    const uint32_t* P = mat ? P20 : P10;

    f32x2 acc[4] = {};
    #pragma unroll 8
    for (int m = 0; m < n; m += 4) {
        uint64_t aw = *reinterpret_cast<const uint64_t*>(adj + m);   // uniform -> s_load
        int j = (int)((uint32_t)(aw >> shamt) & 0xffffu);
        uint2 u = *reinterpret_cast<const uint2*>(P + (size_t)j * 32 + cq * 2);
        acc[0] += upk8<0>(u.x);
        acc[1] += upk8<1>(u.x);
        acc[2] += upk8<0>(u.y);
        acc[3] += upk8<1>(u.y);
    }
    #pragma unroll
    for (int k = 0; k < 4; ++k) {
        acc[k].x += __shfl_xor(acc[k].x, 16); acc[k].y += __shfl_xor(acc[k].y, 16);
        acc[k].x += __shfl_xor(acc[k].x, 32); acc[k].y += __shfl_xor(acc[k].y, 32);
    }

    if (nb == 0) {
        float di = (mat ? d2 : d1)[i];
        float o[8];
        #pragma unroll
        for (int k = 0; k < 4; ++k) { o[2 * k] = di * acc[k].x; o[2 * k + 1] = di * acc[k].y; }

        uint4 rv;
        rv.x = packbf(o[0], o[1]); rv.y = packbf(o[2], o[3]);
        rv.z = packbf(o[4], o[5]); rv.w = packbf(o[6], o[7]);
        *reinterpret_cast<uint4*>(rfb + (size_t)i * RF + 128 + mat * 128 + cq * 8) = rv;

        float s1 = d1[i], s2 = d2[i];
        uint2 v1, v2;
        v1.x = pk8<0>(s1 * o[0], s1 * o[1], 0u);
        v1.x = pk8<1>(s1 * o[2], s1 * o[3], v1.x);
        v1.y = pk8<0>(s1 * o[4], s1 * o[5], 0u);
        v1.y = pk8<1>(s1 * o[6], s1 * o[7], v1.y);
        v2.x = pk8<0>(s2 * o[0], s2 * o[1], 0u);
        v2.x = pk8<1>(s2 * o[2], s2 * o[3], v2.x);
        v2.y = pk8<0>(s2 * o[4], s2 * o[5], 0u);
        v2.y = pk8<1>(s2 * o[6], s2 * o[7], v2.y);
        *reinterpret_cast<uint2*>(P11 + (size_t)i * 64 + mat * 32 + cq * 2) = v1;
        *reinterpret_cast<uint2*>(P21 + (size_t)i * 64 + mat * 32 + cq * 2) = v2;
    }
}

// ---------------------------------------------------------------------------
// 4b) hop-2 gather (fp8 operand), barrier-free, segment-grouped, scalar adj.
//     Grid 4096 blocks: seg = b>>10 (mat=seg>>1, half=seg&1), i = (b&1023)*4+wv.
__global__ __launch_bounds__(256) void gather_k2(
    const uint16_t* __restrict__ adj1, const uint16_t* __restrict__ adj2,
    const int* __restrict__ deg1p, const int* __restrict__ deg2p,
    const uint32_t* __restrict__ P11, const uint32_t* __restrict__ P21,
    const float* __restrict__ d1, const float* __restrict__ d2,
    uint16_t* __restrict__ rfb)
{
    int wv   = threadIdx.x >> 6;
    int lane = threadIdx.x & 63;
    int seg  = blockIdx.x >> 10;
    int i    = __builtin_amdgcn_readfirstlane((blockIdx.x & 1023) * 4 + wv);
    int mat  = seg >> 1;
    int half = seg & 1;
    int nb = lane >> 4, cq = lane & 15;
    int shamt = lane & 48;               // nb*16

    const uint16_t* adj = mat ? adj2 + (size_t)i * CAP2 : adj1 + (size_t)i * CAP1;
    int n = (mat ? deg2p : deg1p)[i];
    const uint32_t* P = (mat ? P21 : P11) + half * 32 + cq * 2;

    f32x2 acc[4] = {};
    #pragma unroll 8
    for (int m = 0; m < n; m += 4) {
        uint64_t aw = *reinterpret_cast<const uint64_t*>(adj + m);   // uniform -> s_load
        int j = (int)((uint32_t)(aw >> shamt) & 0xffffu);
        uint2 u = *reinterpret_cast<const uint2*>(P + (size_t)j * 64);
        acc[0] += upk8<0>(u.x);
        acc[1] += upk8<1>(u.x);
        acc[2] += upk8<0>(u.y);
        acc[3] += upk8<1>(u.y);
    }
    #pragma unroll
    for (int k = 0; k < 4; ++k) {
        acc[k].x += __shfl_xor(acc[k].x, 16); acc[k].y += __shfl_xor(acc[k].y, 16);
        acc[k].x += __shfl_xor(acc[k].x, 32); acc[k].y += __shfl_xor(acc[k].y, 32);
    }

    if (nb == 0) {
        float di = (mat ? d2 : d1)[i];
        int colbase = 384 + mat * 256 + half * 128 + cq * 8;
        uint4 rv;
        rv.x = packbf(di * acc[0].x, di * acc[0].y);
        rv.y = packbf(di * acc[1].x, di * acc[1].y);
        rv.z = packbf(di * acc[2].x, di * acc[2].y);
        rv.w = packbf(di * acc[3].x, di * acc[3].y);
        *reinterpret_cast<uint4*>(rfb + (size_t)i * RF + colbase) = rv;
    }
}

// ---------------------------------------------------------------------------
// 5) classifier GEMM over bf16 rf: out = rf @ Wc + bc. Wave-per-row.
__global__ __launch_bounds__(256) void cls_bf(
    const uint16_t* __restrict__ rfb, const float* __restrict__ Wc,
    const float* __restrict__ bc, float* __restrict__ out)
{
    int wave = threadIdx.x >> 6;
    int lane = threadIdx.x & 63;
    int row  = blockIdx.x * 4 + wave;

    const uint32_t* rp = reinterpret_cast<const uint32_t*>(rfb + (size_t)row * RF);
    float acc[10] = {};
    #pragma unroll
    for (int k7 = 0; k7 < 7; ++k7) {
        int k = k7 * 64 + lane;          // uint index 0..447 (col pair 2k,2k+1)
        uint32_t u = rp[k];
        float x0 = __uint_as_float(u << 16);
        float x1 = __uint_as_float(u & 0xffff0000u);
        const float* w = Wc + (size_t)k * 20;
        #pragma unroll
        for (int c = 0; c < 10; ++c) acc[c] += x0 * w[c] + x1 * w[10 + c];
    }
    #pragma unroll
    for (int c = 0; c < 10; ++c)
        #pragma unroll
        for (int off = 32; off; off >>= 1) acc[c] += __shfl_down(acc[c], off);

    if (lane == 0) {
        #pragma unroll
        for (int c = 0; c < 10; ++c) out[(size_t)row * 10 + c] = acc[c] + bc[c];
    }
}

// ---------------------------------------------------------------------------
extern "C" void kernel_launch(void* const* d_in, const int* in_sizes, int n_in,
                              void* d_out, int out_size, void* d_ws, size_t ws_size,
                              hipStream_t stream) {
    const float* X       = (const float*)d_in[0];
    const int*   ei      = (const int*)d_in[1];
    const float* W_embed = (const float*)d_in[2];
    const float* b_embed = (const float*)d_in[3];
    const float* W_cls   = (const float*)d_in[4];
    const float* b_cls   = (const float*)d_in[5];
    float* out = (float*)d_out;

    int nE = in_sizes[1] / 2;

    // workspace layout (all 16B-aligned)
    uint32_t* Abits = (uint32_t*)d_ws;                         // 2 MB
    float* d1 = (float*)(Abits + (size_t)NN * NW);             // 16 KB
    float* d2 = d1 + NN;                                       // 16 KB
    uint16_t* rfb = (uint16_t*)(d2 + NN);                      // 7.34 MB bf16 [NN][RF]
    uint32_t* P1_0 = (uint32_t*)(rfb + (size_t)NN * RF);       // fp8 [NN+1][128] = 512 KB
    uint32_t* P2_0 = P1_0 + (size_t)(NN + 1) * 32;
    uint32_t* P1_1 = P2_0 + (size_t)(NN + 1) * 32;             // fp8 [NN+1][256] = 1 MB
    uint32_t* P2_1 = P1_1 + (size_t)(NN + 1) * 64;
    uint16_t* Wt_hi = (uint16_t*)(P2_1 + (size_t)(NN + 1) * 64);  // 256 KB
    uint16_t* Wt_lo = Wt_hi + (size_t)HID * IN_DIM;            // 256 KB
    float* partials = (float*)(Wt_lo + (size_t)HID * IN_DIM);  // 8 MB [KS=4][NN][128]
    uint16_t* adj1 = (uint16_t*)(partials + (size_t)KS * NN * HID); // 512 KB
    uint16_t* adj2 = adj1 + (size_t)NN * CAP1;                 // 8 MB
    int* deg1p = (int*)(adj2 + (size_t)NN * CAP2);             // 16 KB
    int* deg2p = deg1p + NN;                                   // 16 KB

    prep<<<641, 256, 0, stream>>>(Abits, P1_0, P2_0, P1_1, P2_1,
                                  W_embed, Wt_hi, Wt_lo);
    scatter_edges<<<(nE + 255) / 256, 256, 0, stream>>>(ei, Abits, nE);
    twohop2<<<NN / 4, 256, 0, stream>>>(Abits, adj1, adj2, deg1p, deg2p, d1, d2);

    embed_mfma<<<dim3(NN / 32, KS), 128, 0, stream>>>(X, Wt_hi, Wt_lo, partials);
    embed_reduce<<<(NN * HID / 4) / 256, 256, 0, stream>>>(partials, b_embed, d1, d2,
                                                           rfb, P1_0, P2_0);

    gather_k1<<<NN * 2 * 64 / 256, 256, 0, stream>>>(
        adj1, adj2, deg1p, deg2p, P1_0, P2_0, d1, d2, rfb, P1_1, P2_1);
    gather_k2<<<NN * 4 * 64 / 256, 256, 0, stream>>>(
        adj1, adj2, deg1p, deg2p, P1_1, P2_1, d1, d2, rfb);

    cls_bf<<<NN / 4, 256, 0, stream>>>(rfb, W_cls, b_cls, out);
}

// Round 16
// 79.504 us; speedup vs baseline: 1.0809x; 1.0501x over previous
//
#include <hip/hip_runtime.h>
#include <hip/hip_bf16.h>
#include <stdint.h>

// Problem constants (match reference)
#define NN      4096
#define IN_DIM  1024
#define HID     128
#define RF      896          // (2^(K+1)-1)*HID
#define NW      128          // words per bitmask row (4096/32)
#define CAP1    64           // adj1 stride (1-hop deg ~16, max ~40)
#define CAP2    1024         // adj2 stride (2-hop deg ~240)
#define KS      4            // split-K chunks for embed gemm (2 sub-chunks each)
#define KC      256          // columns per kc block (2 x 128 staging sub-chunks)

typedef __attribute__((ext_vector_type(8))) short   bf16x8;
typedef __attribute__((ext_vector_type(4))) float   f32x4;
typedef __attribute__((ext_vector_type(2))) float   f32x2;

static __device__ __forceinline__ uint16_t f2bf(float f) {
    __hip_bfloat16 h = __float2bfloat16(f);   // RNE
    return *reinterpret_cast<uint16_t*>(&h);
}
static __device__ __forceinline__ float bf2f(uint16_t u) {
    __hip_bfloat16 h = *reinterpret_cast<__hip_bfloat16*>(&u);
    return __bfloat162float(h);
}
static __device__ __forceinline__ uint32_t packbf(float lo, float hi) {
    return (uint32_t)f2bf(lo) | ((uint32_t)f2bf(hi) << 16);
}
// fp8 e4m3 pack/unpack via gfx950 HW converters (select arg must be imm const)
template<int HI>
static __device__ __forceinline__ uint32_t pk8(float a, float b, uint32_t old) {
    return __builtin_amdgcn_cvt_pk_fp8_f32(a, b, old, HI);
}
template<int HI>
static __device__ __forceinline__ f32x2 upk8(uint32_t u) {
    return __builtin_amdgcn_cvt_pk_f32_fp8(u, HI);
}

// ---------------------------------------------------------------------------
// 0) prep: zero Abits (blocks 0..511), zero P pad rows (block 512),
//    convert W -> transposed bf16 (blocks 513..640, 128 thr active).
//    Single bf16 (no lo-split): embed output is fp8-quantized downstream,
//    so bf16 rounding (~0.2% rel) is negligible vs fp8's 3.6%.
__global__ __launch_bounds__(256) void prep(
    uint32_t* __restrict__ Abits, uint32_t* __restrict__ p10, uint32_t* __restrict__ p20,
    uint32_t* __restrict__ p11, uint32_t* __restrict__ p21,
    const float* __restrict__ W, uint16_t* __restrict__ Wt_hi)
{
    int b = blockIdx.x, t = threadIdx.x;
    if (b < 512) {
        reinterpret_cast<uint4*>(Abits)[b * 256 + t] = make_uint4(0, 0, 0, 0);
    } else if (b == 512) {
        // fp8 pad rows: P*_0 = 128 B (32 uints), P*_1 = 256 B (64 uints)
        if (t < 32) { p10[(size_t)NN * 32 + t] = 0; p20[(size_t)NN * 32 + t] = 0; }
        if (t < 64) { p11[(size_t)NN * 64 + t] = 0; p21[(size_t)NN * 64 + t] = 0; }
    } else {
        if (t < 128) {
            int n  = t;
            int k0 = (b - 513) * 8;
            uint16_t h[8];
            #pragma unroll
            for (int j = 0; j < 8; ++j)
                h[j] = f2bf(W[(size_t)(k0 + j) * HID + n]);
            ushort4* ph = reinterpret_cast<ushort4*>(Wt_hi + (size_t)n * IN_DIM + k0);
            ph[0] = make_ushort4(h[0], h[1], h[2], h[3]);
            ph[1] = make_ushort4(h[4], h[5], h[6], h[7]);
        }
    }
}

// ---------------------------------------------------------------------------
// 1) scatter edges into bitmask adjacency  A[src][dst] = 1
__global__ void scatter_edges(const int* __restrict__ ei, uint32_t* __restrict__ Abits, int nE) {
    int e = blockIdx.x * blockDim.x + threadIdx.x;
    if (e < nE) {
        int s = ei[e];
        int d = ei[nE + e];
        atomicOr(&Abits[(size_t)s * NW + (d >> 5)], 1u << (d & 31));
    }
}

// ---------------------------------------------------------------------------
// 2) twohop2: bit-sliced threshold counters, wave-per-row (4 waves/block).
#define UPD(v) { s3x |= s2x & (v).x; s2x |= s1x & (v).x; s1x |= (v).x; \
                 s3y |= s2y & (v).y; s2y |= s1y & (v).y; s1y |= (v).y; }
__global__ __launch_bounds__(256) void twohop2(
    const uint32_t* __restrict__ Abits,
    uint16_t* __restrict__ adj1, uint16_t* __restrict__ adj2,
    int* __restrict__ deg1p, int* __restrict__ deg2p,
    float* __restrict__ d1, float* __restrict__ d2)
{
    __shared__ uint16_t l1s[4][CAP1];

    int wv = threadIdx.x >> 6, lane = threadIdx.x & 63;
    int i = blockIdx.x * 4 + wv;

    uint2 sv = *reinterpret_cast<const uint2*>(&Abits[(size_t)i * NW + lane * 2]);

    // ---- adj1: scan + emit
    int pc1 = __popc(sv.x) + __popc(sv.y);
    int x1 = pc1;
    #pragma unroll
    for (int off = 1; off < 64; off <<= 1) {
        int y = __shfl_up(x1, off);
        if (lane >= off) x1 += y;
    }
    int tot1 = __shfl(x1, 63);
    int o = x1 - pc1;                       // exclusive prefix
    {
        uint32_t b = sv.x;
        while (b) { int bb = __ffs(b) - 1; b &= b - 1;
                    uint16_t v = (uint16_t)(lane * 64 + bb);
                    l1s[wv][o] = v; adj1[(size_t)i * CAP1 + o] = v; ++o; }
        b = sv.y;
        while (b) { int bb = __ffs(b) - 1; b &= b - 1;
                    uint16_t v = (uint16_t)(lane * 64 + 32 + bb);
                    l1s[wv][o] = v; adj1[(size_t)i * CAP1 + o] = v; ++o; }
    }
    int n1 = (tot1 + 3) & ~3;
    if (lane == 0) {
        for (int z = tot1; z < n1; ++z) adj1[(size_t)i * CAP1 + z] = (uint16_t)NN;
        deg1p[i] = n1;
        d1[i] = rsqrtf((float)tot1 + 1e-8f);
    }
    __syncthreads();

    // ---- path-count thresholds over neighbors
    uint32_t s1x = 0, s2x = 0, s3x = 0, s1y = 0, s2y = 0, s3y = 0;
    int m = 0;
    for (; m + 4 <= tot1; m += 4) {
        int k0 = l1s[wv][m], k1 = l1s[wv][m + 1], k2 = l1s[wv][m + 2], k3 = l1s[wv][m + 3];
        uint2 a = *reinterpret_cast<const uint2*>(&Abits[(size_t)k0 * NW + lane * 2]);
        uint2 b = *reinterpret_cast<const uint2*>(&Abits[(size_t)k1 * NW + lane * 2]);
        uint2 c = *reinterpret_cast<const uint2*>(&Abits[(size_t)k2 * NW + lane * 2]);
        uint2 d = *reinterpret_cast<const uint2*>(&Abits[(size_t)k3 * NW + lane * 2]);
        UPD(a); UPD(b); UPD(c); UPD(d);
    }
    for (; m < tot1; ++m) {
        int k = l1s[wv][m];
        uint2 a = *reinterpret_cast<const uint2*>(&Abits[(size_t)k * NW + lane * 2]);
        UPD(a);
    }

    uint32_t iwx = ((i >> 5) == lane * 2)     ? (1u << (i & 31)) : 0u;
    uint32_t iwy = ((i >> 5) == lane * 2 + 1) ? (1u << (i & 31)) : 0u;
    uint32_t a2x = (s1x & ~sv.x & ~iwx) | (s2x & (sv.x ^ iwx)) | (s3x & (sv.x & iwx));
    uint32_t a2y = (s1y & ~sv.y & ~iwy) | (s2y & (sv.y ^ iwy)) | (s3y & (sv.y & iwy));

    // ---- adj2: scan + emit
    int pc2 = __popc(a2x) + __popc(a2y);
    int x2 = pc2;
    #pragma unroll
    for (int off = 1; off < 64; off <<= 1) {
        int y = __shfl_up(x2, off);
        if (lane >= off) x2 += y;
    }
    int tot2 = __shfl(x2, 63);
    o = x2 - pc2;
    {
        uint32_t b = a2x;
        while (b) { int bb = __ffs(b) - 1; b &= b - 1;
                    adj2[(size_t)i * CAP2 + o] = (uint16_t)(lane * 64 + bb); ++o; }
        b = a2y;
        while (b) { int bb = __ffs(b) - 1; b &= b - 1;
                    adj2[(size_t)i * CAP2 + o] = (uint16_t)(lane * 64 + 32 + bb); ++o; }
    }
    int n2 = (tot2 + 3) & ~3;
    if (lane == 0) {
        for (int z = tot2; z < n2; ++z) adj2[(size_t)i * CAP2 + z] = (uint16_t)NN;
        deg2p[i] = n2;
        d2[i] = rsqrtf((float)tot2 + 1e-8f);
    }
}

// ---------------------------------------------------------------------------
// 3b) embed MFMA GEMM, single bf16, split-K (KS=4; each block loops over
//     two 128-wide k-sub-chunks, accumulating in-register).
#define XSTR 136
__global__ __launch_bounds__(128) void embed_mfma(
    const float* __restrict__ X, const uint16_t* __restrict__ Wt_hi,
    float* __restrict__ partials)
{
    __shared__ uint16_t XhiS[32][XSTR];
    __shared__ uint16_t WS[128][XSTR];

    int t  = threadIdx.x;
    int m0 = blockIdx.x * 32;
    int kc = blockIdx.y;

    int w = t >> 6, lane = t & 63;
    int nr = lane & 15, g = lane >> 4;
    int arow = w * 16 + nr;

    f32x4 acc[8] = {};

    #pragma unroll
    for (int kc2 = 0; kc2 < 2; ++kc2) {
        int kOff = kc * KC + kc2 * 128;

        // stage X sub-tile (32 x 128 fp32) -> bf16
        #pragma unroll
        for (int u = 0; u < 8; ++u) {
            int q = u * 128 + t;
            int row = q >> 5, c4 = q & 31;
            float4 xv = *reinterpret_cast<const float4*>(
                X + (size_t)(m0 + row) * IN_DIM + kOff + c4 * 4);
            ushort4 hv;
            hv.x = f2bf(xv.x); hv.y = f2bf(xv.y);
            hv.z = f2bf(xv.z); hv.w = f2bf(xv.w);
            *reinterpret_cast<ushort4*>(&XhiS[row][c4 * 4]) = hv;
        }
        // stage W sub-tile (128 n x 128 k)
        #pragma unroll
        for (int u = 0; u < 16; ++u) {
            int q = u * 128 + t;
            int n = q >> 4, ck = q & 15;
            *reinterpret_cast<uint4*>(&WS[n][ck * 8]) =
                *reinterpret_cast<const uint4*>(Wt_hi + (size_t)n * IN_DIM + kOff + ck * 8);
        }
        __syncthreads();

        bf16x8 ah[4];
        #pragma unroll
        for (int s = 0; s < 4; ++s)
            ah[s] = *reinterpret_cast<const bf16x8*>(&XhiS[arow][s * 32 + g * 8]);

        #pragma unroll
        for (int s = 0; s < 4; ++s)
            #pragma unroll
            for (int nf = 0; nf < 8; ++nf) {
                bf16x8 bb = *reinterpret_cast<const bf16x8*>(&WS[nf * 16 + nr][s * 32 + g * 8]);
                acc[nf] = __builtin_amdgcn_mfma_f32_16x16x32_bf16(ah[s], bb, acc[nf], 0, 0, 0);
            }
        __syncthreads();   // protect LDS before next sub-chunk restage
    }

    float* part = partials + (size_t)kc * NN * HID;
    #pragma unroll
    for (int nf = 0; nf < 8; ++nf)
        #pragma unroll
        for (int r = 0; r < 4; ++r)
            part[(size_t)(m0 + w * 16 + g * 4 + r) * HID + nf * 16 + nr] = acc[nf][r];
}

// ---------------------------------------------------------------------------
// 3c) reduce split-K partials + bias + relu -> rf bf16 (cols 0:128) +
//     P1_0/P2_0 in fp8 e4m3 (pre-scaled by d1/d2)
__global__ void embed_reduce(const float* __restrict__ partials, const float* __restrict__ bias,
                             const float* __restrict__ d1, const float* __restrict__ d2,
                             uint16_t* __restrict__ rfb, uint32_t* __restrict__ P1,
                             uint32_t* __restrict__ P2) {
    int idx = blockIdx.x * blockDim.x + threadIdx.x;
    size_t off = (size_t)idx * 4;
    int row = (int)(off >> 7);
    int col = (int)(off & 127);

    float4 s = make_float4(0.f, 0.f, 0.f, 0.f);
    #pragma unroll
    for (int kc = 0; kc < KS; ++kc) {
        float4 p = *reinterpret_cast<const float4*>(partials + (size_t)kc * NN * HID + off);
        s.x += p.x; s.y += p.y; s.z += p.z; s.w += p.w;
    }
    float4 bv = *reinterpret_cast<const float4*>(bias + col);
    float4 v;
    v.x = fmaxf(s.x + bv.x, 0.f);
    v.y = fmaxf(s.y + bv.y, 0.f);
    v.z = fmaxf(s.z + bv.z, 0.f);
    v.w = fmaxf(s.w + bv.w, 0.f);

    uint2 rv;
    rv.x = packbf(v.x, v.y); rv.y = packbf(v.z, v.w);
    *reinterpret_cast<uint2*>(rfb + (size_t)row * RF + col) = rv;

    float s1 = d1[row], s2 = d2[row];
    uint32_t w1 = pk8<0>(s1 * v.x, s1 * v.y, 0u);
    w1 = pk8<1>(s1 * v.z, s1 * v.w, w1);
    P1[(size_t)row * 32 + (col >> 2)] = w1;
    uint32_t w2 = pk8<0>(s2 * v.x, s2 * v.y, 0u);
    w2 = pk8<1>(s2 * v.z, s2 * v.w, w2);
    P2[(size_t)row * 32 + (col >> 2)] = w2;
}

// ---------------------------------------------------------------------------
// 4a) hop-1 gather (fp8 operand). Wave task gw: i = gw>>1, mat = gw&1.
//     Scalar adj fetch; lane reads uint2 = 8 fp8 values.
__global__ __launch_bounds__(256) void gather_k1(
    const uint16_t* __restrict__ adj1, const uint16_t* __restrict__ adj2,
    const int* __restrict__ deg1p, const int* __restrict__ deg2p,
    const uint32_t* __restrict__ P10, const uint32_t* __restrict__ P20,
    const float* __restrict__ d1, const float* __restrict__ d2,
    uint16_t* __restrict__ rfb, uint32_t* __restrict__ P11, uint32_t* __restrict__ P21)
{
    int lane = threadIdx.x & 63;
    int gw   = __builtin_amdgcn_readfirstlane((blockIdx.x * 256 + threadIdx.x) >> 6);
    int i    = gw >> 1;
    int mat  = gw & 1;
    int nb = lane >> 4, cq = lane & 15;
    int shamt = lane & 48;               // nb*16

    const uint16_t* adj = mat ? adj2 + (size_t)i * CAP2 : adj1 + (size_t)i * CAP1;
    int n = (mat ? deg2p : deg1p)[i];
    const uint32_t* P = mat ? P20 : P10;

    f32x2 acc[4] = {};
    #pragma unroll 8
    for (int m = 0; m < n; m += 4) {
        uint64_t aw = *reinterpret_cast<const uint64_t*>(adj + m);   // uniform -> s_load
        int j = (int)((uint32_t)(aw >> shamt) & 0xffffu);
        uint2 u = *reinterpret_cast<const uint2*>(P + (size_t)j * 32 + cq * 2);
        acc[0] += upk8<0>(u.x);
        acc[1] += upk8<1>(u.x);
        acc[2] += upk8<0>(u.y);
        acc[3] += upk8<1>(u.y);
    }
    #pragma unroll
    for (int k = 0; k < 4; ++k) {
        acc[k].x += __shfl_xor(acc[k].x, 16); acc[k].y += __shfl_xor(acc[k].y, 16);
        acc[k].x += __shfl_xor(acc[k].x, 32); acc[k].y += __shfl_xor(acc[k].y, 32);
    }

    if (nb == 0) {
        float di = (mat ? d2 : d1)[i];
        float o[8];
        #pragma unroll
        for (int k = 0; k < 4; ++k) { o[2 * k] = di * acc[k].x; o[2 * k + 1] = di * acc[k].y; }

        uint4 rv;
        rv.x = packbf(o[0], o[1]); rv.y = packbf(o[2], o[3]);
        rv.z = packbf(o[4], o[5]); rv.w = packbf(o[6], o[7]);
        *reinterpret_cast<uint4*>(rfb + (size_t)i * RF + 128 + mat * 128 + cq * 8) = rv;

        float s1 = d1[i], s2 = d2[i];
        uint2 v1, v2;
        v1.x = pk8<0>(s1 * o[0], s1 * o[1], 0u);
        v1.x = pk8<1>(s1 * o[2], s1 * o[3], v1.x);
        v1.y = pk8<0>(s1 * o[4], s1 * o[5], 0u);
        v1.y = pk8<1>(s1 * o[6], s1 * o[7], v1.y);
        v2.x = pk8<0>(s2 * o[0], s2 * o[1], 0u);
        v2.x = pk8<1>(s2 * o[2], s2 * o[3], v2.x);
        v2.y = pk8<0>(s2 * o[4], s2 * o[5], 0u);
        v2.y = pk8<1>(s2 * o[6], s2 * o[7], v2.y);
        *reinterpret_cast<uint2*>(P11 + (size_t)i * 64 + mat * 32 + cq * 2) = v1;
        *reinterpret_cast<uint2*>(P21 + (size_t)i * 64 + mat * 32 + cq * 2) = v2;
    }
}

// ---------------------------------------------------------------------------
// 4b) hop-2 gather (fp8 operand), barrier-free, segment-grouped, scalar adj.
//     Grid 4096 blocks: seg = b>>10 (mat=seg>>1, half=seg&1), i = (b&1023)*4+wv.
__global__ __launch_bounds__(256) void gather_k2(
    const uint16_t* __restrict__ adj1, const uint16_t* __restrict__ adj2,
    const int* __restrict__ deg1p, const int* __restrict__ deg2p,
    const uint32_t* __restrict__ P11, const uint32_t* __restrict__ P21,
    const float* __restrict__ d1, const float* __restrict__ d2,
    uint16_t* __restrict__ rfb)
{
    int wv   = threadIdx.x >> 6;
    int lane = threadIdx.x & 63;
    int seg  = blockIdx.x >> 10;
    int i    = __builtin_amdgcn_readfirstlane((blockIdx.x & 1023) * 4 + wv);
    int mat  = seg >> 1;
    int half = seg & 1;
    int nb = lane >> 4, cq = lane & 15;
    int shamt = lane & 48;               // nb*16

    const uint16_t* adj = mat ? adj2 + (size_t)i * CAP2 : adj1 + (size_t)i * CAP1;
    int n = (mat ? deg2p : deg1p)[i];
    const uint32_t* P = (mat ? P21 : P11) + half * 32 + cq * 2;

    f32x2 acc[4] = {};
    #pragma unroll 8
    for (int m = 0; m < n; m += 4) {
        uint64_t aw = *reinterpret_cast<const uint64_t*>(adj + m);   // uniform -> s_load
        int j = (int)((uint32_t)(aw >> shamt) & 0xffffu);
        uint2 u = *reinterpret_cast<const uint2*>(P + (size_t)j * 64);
        acc[0] += upk8<0>(u.x);
        acc[1] += upk8<1>(u.x);
        acc[2] += upk8<0>(u.y);
        acc[3] += upk8<1>(u.y);
    }
    #pragma unroll
    for (int k = 0; k < 4; ++k) {
        acc[k].x += __shfl_xor(acc[k].x, 16); acc[k].y += __shfl_xor(acc[k].y, 16);
        acc[k].x += __shfl_xor(acc[k].x, 32); acc[k].y += __shfl_xor(acc[k].y, 32);
    }

    if (nb == 0) {
        float di = (mat ? d2 : d1)[i];
        int colbase = 384 + mat * 256 + half * 128 + cq * 8;
        uint4 rv;
        rv.x = packbf(di * acc[0].x, di * acc[0].y);
        rv.y = packbf(di * acc[1].x, di * acc[1].y);
        rv.z = packbf(di * acc[2].x, di * acc[2].y);
        rv.w = packbf(di * acc[3].x, di * acc[3].y);
        *reinterpret_cast<uint4*>(rfb + (size_t)i * RF + colbase) = rv;
    }
}

// ---------------------------------------------------------------------------
// 5) classifier GEMM over bf16 rf: out = rf @ Wc + bc. Wave-per-row.
__global__ __launch_bounds__(256) void cls_bf(
    const uint16_t* __restrict__ rfb, const float* __restrict__ Wc,
    const float* __restrict__ bc, float* __restrict__ out)
{
    int wave = threadIdx.x >> 6;
    int lane = threadIdx.x & 63;
    int row  = blockIdx.x * 4 + wave;

    const uint32_t* rp = reinterpret_cast<const uint32_t*>(rfb + (size_t)row * RF);
    float acc[10] = {};
    #pragma unroll
    for (int k7 = 0; k7 < 7; ++k7) {
        int k = k7 * 64 + lane;          // uint index 0..447 (col pair 2k,2k+1)
        uint32_t u = rp[k];
        float x0 = __uint_as_float(u << 16);
        float x1 = __uint_as_float(u & 0xffff0000u);
        const float* w = Wc + (size_t)k * 20;
        #pragma unroll
        for (int c = 0; c < 10; ++c) acc[c] += x0 * w[c] + x1 * w[10 + c];
    }
    #pragma unroll
    for (int c = 0; c < 10; ++c)
        #pragma unroll
        for (int off = 32; off; off >>= 1) acc[c] += __shfl_down(acc[c], off);

    if (lane == 0) {
        #pragma unroll
        for (int c = 0; c < 10; ++c) out[(size_t)row * 10 + c] = acc[c] + bc[c];
    }
}

// ---------------------------------------------------------------------------
extern "C" void kernel_launch(void* const* d_in, const int* in_sizes, int n_in,
                              void* d_out, int out_size, void* d_ws, size_t ws_size,
                              hipStream_t stream) {
    const float* X       = (const float*)d_in[0];
    const int*   ei      = (const int*)d_in[1];
    const float* W_embed = (const float*)d_in[2];
    const float* b_embed = (const float*)d_in[3];
    const float* W_cls   = (const float*)d_in[4];
    const float* b_cls   = (const float*)d_in[5];
    float* out = (float*)d_out;

    int nE = in_sizes[1] / 2;

    // workspace layout (all 16B-aligned)
    uint32_t* Abits = (uint32_t*)d_ws;                         // 2 MB
    float* d1 = (float*)(Abits + (size_t)NN * NW);             // 16 KB
    float* d2 = d1 + NN;                                       // 16 KB
    uint16_t* rfb = (uint16_t*)(d2 + NN);                      // 7.34 MB bf16 [NN][RF]
    uint32_t* P1_0 = (uint32_t*)(rfb + (size_t)NN * RF);       // fp8 [NN+1][128] = 512 KB
    uint32_t* P2_0 = P1_0 + (size_t)(NN + 1) * 32;
    uint32_t* P1_1 = P2_0 + (size_t)(NN + 1) * 32;             // fp8 [NN+1][256] = 1 MB
    uint32_t* P2_1 = P1_1 + (size_t)(NN + 1) * 64;
    uint16_t* Wt_hi = (uint16_t*)(P2_1 + (size_t)(NN + 1) * 64);  // 256 KB
    float* partials = (float*)(Wt_hi + (size_t)HID * IN_DIM);  // 8 MB [KS=4][NN][128]
    uint16_t* adj1 = (uint16_t*)(partials + (size_t)KS * NN * HID); // 512 KB
    uint16_t* adj2 = adj1 + (size_t)NN * CAP1;                 // 8 MB
    int* deg1p = (int*)(adj2 + (size_t)NN * CAP2);             // 16 KB
    int* deg2p = deg1p + NN;                                   // 16 KB

    prep<<<641, 256, 0, stream>>>(Abits, P1_0, P2_0, P1_1, P2_1,
                                  W_embed, Wt_hi);
    scatter_edges<<<(nE + 255) / 256, 256, 0, stream>>>(ei, Abits, nE);
    twohop2<<<NN / 4, 256, 0, stream>>>(Abits, adj1, adj2, deg1p, deg2p, d1, d2);

    embed_mfma<<<dim3(NN / 32, KS), 128, 0, stream>>>(X, Wt_hi, partials);
    embed_reduce<<<(NN * HID / 4) / 256, 256, 0, stream>>>(partials, b_embed, d1, d2,
                                                           rfb, P1_0, P2_0);

    gather_k1<<<NN * 2 * 64 / 256, 256, 0, stream>>>(
        adj1, adj2, deg1p, deg2p, P1_0, P2_0, d1, d2, rfb, P1_1, P2_1);
    gather_k2<<<NN * 4 * 64 / 256, 256, 0, stream>>>(
        adj1, adj2, deg1p, deg2p, P1_1, P2_1, d1, d2, rfb);

    cls_bf<<<NN / 4, 256, 0, stream>>>(rfb, W_cls, b_cls, out);
}